// Round 2
// baseline (468.112 us; speedup 1.0000x reference)
//
#include <hip/hip_runtime.h>
#include <hip/hip_bf16.h>
#include <stdint.h>

// W8A8 int8 GEMM + dequant epilogue, MI355X gfx950.
// A (input)  : [M,K] int8, delivered as int32 -> packed to int8 in d_ws
// W (weight) : [N,K] int8, delivered as int32 -> packed to int8 in d_ws
// fp16 reference arrays (bias, scale_input, scale_weight) arrive as float32;
// output is float32 (reference fp16 -> harness "else float*" path).
// out[m,n] = (sum_k A*W + sum_input[m]*zp_w[n]) * si[m]*sw[n] + bias[n]

#define BM 128
#define BN 128
#define BK 64

typedef __attribute__((ext_vector_type(4))) int int32x4;

__device__ __forceinline__ void async_copy16(const uint8_t* g, uint8_t* l) {
  __builtin_amdgcn_global_load_lds(
      (const __attribute__((address_space(1))) uint32_t*)(const void*)g,
      (__attribute__((address_space(3))) uint32_t*)l,  // direct addrspacecast
      16, 0, 0);
}

__global__ __launch_bounds__(256) void pack_kernel(
    const int* __restrict__ A, const int* __restrict__ B,
    uint8_t* __restrict__ A8, uint8_t* __restrict__ B8,
    int nA16, int nTot16) {
  int t = blockIdx.x * blockDim.x + threadIdx.x;
  if (t >= nTot16) return;
  const int4* src;
  uint4* dst;
  if (t < nA16) {
    src = (const int4*)A + (size_t)t * 4;
    dst = (uint4*)A8 + t;
  } else {
    int u = t - nA16;
    src = (const int4*)B + (size_t)u * 4;
    dst = (uint4*)B8 + u;
  }
  uint32_t w[4];
#pragma unroll
  for (int q = 0; q < 4; ++q) {
    int4 v = src[q];
    w[q] = (uint32_t)(v.x & 255) | ((uint32_t)(v.y & 255) << 8) |
           ((uint32_t)(v.z & 255) << 16) | ((uint32_t)(v.w & 255) << 24);
  }
  *dst = make_uint4(w[0], w[1], w[2], w[3]);
}

template <bool PACKED>
__global__ __launch_bounds__(256) void w8a8_gemm(
    const uint8_t* __restrict__ A8, const uint8_t* __restrict__ B8,
    const int* __restrict__ A32, const int* __restrict__ B32,
    const float* __restrict__ bias,
    const float* __restrict__ s_in,
    const float* __restrict__ s_w,
    const float* __restrict__ sum_in,
    const int* __restrict__ zp_w,
    float* __restrict__ out,
    int M, int N, int K) {
  __shared__ uint8_t As[BM * BK];  // 8 KiB
  __shared__ uint8_t Bs[BN * BK];  // 8 KiB

  const int tid = threadIdx.x;
  const int bm = blockIdx.y, bn = blockIdx.x;
  const int row0 = bm * BM, col0 = bn * BN;
  const int wave = tid >> 6, lane = tid & 63;
  const int quad = lane >> 4, r = lane & 15;
  const int wm = (wave >> 1) * 64, wn = (wave & 1) * 64;

  // staging geometry: thread t owns bytes [t*16, t*16+16) of each 8 KiB tile
  // (and the same +4096). Contiguous in lane order -> global_load_lds-safe
  // (wave-uniform base + lane*16).
  const int lin = tid * 16;
  const int srow = lin >> 6;  // 0..63 within tile
  const int scol = lin & 63;
  const size_t sK = (size_t)K;

  int32x4 acc[4][4] = {};

  for (int k0 = 0; k0 < K; k0 += BK) {
    if (PACKED) {
      const uint8_t* ag = A8 + (size_t)(row0 + srow) * sK + k0 + scol;
      const uint8_t* bg = B8 + (size_t)(col0 + srow) * sK + k0 + scol;
      async_copy16(ag, &As[lin]);
      async_copy16(ag + 64 * sK, &As[lin + 4096]);
      async_copy16(bg, &Bs[lin]);
      async_copy16(bg + 64 * sK, &Bs[lin + 4096]);
    } else {
      // fallback: read int32, pack in VALU, ds_write (used only if ws too small)
#pragma unroll
      for (int c = 0; c < 2; ++c) {
        const int* ag = A32 + (size_t)(row0 + srow + c * 64) * sK + k0 + scol;
        const int* bg = B32 + (size_t)(col0 + srow + c * 64) * sK + k0 + scol;
        int32x4 pa, pb;
#pragma unroll
        for (int q = 0; q < 4; ++q) {
          int4 va = ((const int4*)ag)[q];
          int4 vb = ((const int4*)bg)[q];
          pa[q] = (int)((uint32_t)(va.x & 255) | ((uint32_t)(va.y & 255) << 8) |
                        ((uint32_t)(va.z & 255) << 16) | ((uint32_t)(va.w & 255) << 24));
          pb[q] = (int)((uint32_t)(vb.x & 255) | ((uint32_t)(vb.y & 255) << 8) |
                        ((uint32_t)(vb.z & 255) << 16) | ((uint32_t)(vb.w & 255) << 24));
        }
        *(int32x4*)&As[lin + c * 4096] = pa;
        *(int32x4*)&Bs[lin + c * 4096] = pb;
      }
    }
    __syncthreads();  // compiler drains vmcnt(0)/lgkmcnt(0) here

    int32x4 afrag[4], bfrag[4];
#pragma unroll
    for (int i = 0; i < 4; ++i)
      afrag[i] = *(const int32x4*)&As[(wm + i * 16 + r) * 64 + quad * 16];
#pragma unroll
    for (int j = 0; j < 4; ++j)
      bfrag[j] = *(const int32x4*)&Bs[(wn + j * 16 + r) * 64 + quad * 16];
#pragma unroll
    for (int i = 0; i < 4; ++i)
#pragma unroll
      for (int j = 0; j < 4; ++j)
        acc[i][j] = __builtin_amdgcn_mfma_i32_16x16x64_i8(afrag[i], bfrag[j],
                                                          acc[i][j], 0, 0, 0);
    __syncthreads();
  }

  // Epilogue: C/D layout col=lane&15, row=quad*4+reg (dtype-independent).
  float swj[4], zpj[4], bj[4];
#pragma unroll
  for (int j = 0; j < 4; ++j) {
    int gc = col0 + wn + j * 16 + r;
    swj[j] = s_w[gc];
    zpj[j] = (float)zp_w[gc];
    bj[j] = bias[gc];
  }
#pragma unroll
  for (int i = 0; i < 4; ++i) {
#pragma unroll
    for (int t = 0; t < 4; ++t) {
      int gr = row0 + wm + i * 16 + quad * 4 + t;
      float siv = s_in[gr];
      float suv = sum_in[gr];
      float* orow = out + (size_t)gr * N + col0 + wn + r;
#pragma unroll
      for (int j = 0; j < 4; ++j) {
        float v = ((float)acc[i][j][t] + suv * zpj[j]) * (siv * swj[j]) + bj[j];
        orow[j * 16] = v;
      }
    }
  }
}

extern "C" void kernel_launch(void* const* d_in, const int* in_sizes, int n_in,
                              void* d_out, int out_size, void* d_ws, size_t ws_size,
                              hipStream_t stream) {
  const int* x_q = (const int*)d_in[0];        // int8 -> int32
  const int* w_q = (const int*)d_in[1];        // int8 -> int32
  const float* bias = (const float*)d_in[2];   // fp16 -> float32
  const float* s_in = (const float*)d_in[3];   // fp16 -> float32
  const float* s_w = (const float*)d_in[4];    // fp16 -> float32
  const float* sum_in = (const float*)d_in[5]; // float32
  const int* zp_w = (const int*)d_in[6];       // int16 -> int32
  float* out = (float*)d_out;                  // fp16 -> float32

  const int M = in_sizes[3];
  const int N = in_sizes[2];
  const int K = in_sizes[0] / M;

  const size_t needA = (size_t)M * K;
  const size_t needB = (size_t)N * K;
  dim3 grid(N / BN, M / BM), block(256);

  if (ws_size >= needA + needB) {
    uint8_t* A8 = (uint8_t*)d_ws;
    uint8_t* B8 = A8 + needA;
    const int nA16 = (int)(needA / 16);
    const int nTot16 = (int)((needA + needB) / 16);
    pack_kernel<<<(nTot16 + 255) / 256, 256, 0, stream>>>(x_q, w_q, A8, B8,
                                                          nA16, nTot16);
    w8a8_gemm<true><<<grid, block, 0, stream>>>(A8, B8, nullptr, nullptr, bias,
                                                s_in, s_w, sum_in, zp_w, out,
                                                M, N, K);
  } else {
    w8a8_gemm<false><<<grid, block, 0, stream>>>(nullptr, nullptr, x_q, w_q,
                                                 bias, s_in, s_w, sum_in, zp_w,
                                                 out, M, N, K);
  }
}

// Round 3
// 422.020 us; speedup vs baseline: 1.1092x; 1.1092x over previous
//
#include <hip/hip_runtime.h>
#include <hip/hip_bf16.h>
#include <stdint.h>

// W8A8 int8 GEMM + dequant epilogue, MI355X gfx950.
// A (input)  : [M,K] int8, delivered as int32 -> packed to int8 in d_ws
// W (weight) : [N,K] int8, delivered as int32 -> packed to int8 in d_ws
// fp16 reference arrays (bias, scale_input, scale_weight) arrive as float32;
// output is float32.
// out[m,n] = (sum_k A*W + sum_input[m]*zp_w[n]) * si[m]*sw[n] + bias[n]

#define BM 128
#define BN 128
#define BK 128  // R3: was 64 — 32 MFMAs per barrier-pair instead of 16

typedef __attribute__((ext_vector_type(4))) int int32x4;

__device__ __forceinline__ void async_copy16(const uint8_t* g, uint8_t* l) {
  __builtin_amdgcn_global_load_lds(
      (const __attribute__((address_space(1))) uint32_t*)(const void*)g,
      (__attribute__((address_space(3))) uint32_t*)l,
      16, 0, 0);
}

// R3: coalesced pack — one int4 (4 int8-as-int32) per thread -> one uint32.
__global__ __launch_bounds__(256) void pack_kernel(
    const int* __restrict__ A, const int* __restrict__ B,
    uint8_t* __restrict__ A8, uint8_t* __restrict__ B8,
    int nA4, int nTot4) {
  int t = blockIdx.x * blockDim.x + threadIdx.x;
  if (t >= nTot4) return;
  const int4* src;
  uint32_t* dst;
  if (t < nA4) {
    src = (const int4*)A + t;
    dst = (uint32_t*)A8 + t;
  } else {
    int u = t - nA4;
    src = (const int4*)B + u;
    dst = (uint32_t*)B8 + u;
  }
  int4 v = *src;
  *dst = (uint32_t)(v.x & 255) | ((uint32_t)(v.y & 255) << 8) |
         ((uint32_t)(v.z & 255) << 16) | ((uint32_t)(v.w & 255) << 24);
}

// Packed-path GEMM: BK=128, XOR-swizzled LDS chunks.
// LDS layout: row r (128 B) stores global chunk cg at slot cs = cg ^ ((r>>1)&7).
// global_load_lds needs lane-order-contiguous LDS dests, so the swizzle is
// applied to the *global source* chunk index per lane; within-row chunk
// permutation keeps the 128-B row read fully coalesced.
__global__ __launch_bounds__(256) void w8a8_gemm(
    const uint8_t* __restrict__ A8, const uint8_t* __restrict__ B8,
    const float* __restrict__ bias,
    const float* __restrict__ s_in,
    const float* __restrict__ s_w,
    const float* __restrict__ sum_in,
    const int* __restrict__ zp_w,
    float* __restrict__ out,
    int M, int N, int K) {
  __shared__ uint8_t As[BM * BK];  // 16 KiB
  __shared__ uint8_t Bs[BN * BK];  // 16 KiB

  const int tid = threadIdx.x;
  const int bm = blockIdx.y, bn = blockIdx.x;
  const int row0 = bm * BM, col0 = bn * BN;
  const int wave = tid >> 6, lane = tid & 63;
  const int quad = lane >> 4, r = lane & 15;
  const int wm = (wave >> 1) * 64, wn = (wave & 1) * 64;
  const size_t sK = (size_t)K;

  // staging: issue p (0..3) covers rows [p*32, p*32+32); thread owns
  // row_s = tid>>3 within the issue, stored chunk cs = tid&7,
  // global chunk cg = cs ^ swz where swz = (row>>1)&7 = (tid>>4)&7.
  const int row_s = tid >> 3;
  const int cg = (tid & 7) ^ ((tid >> 4) & 7);
  const int ldst = tid * 16;  // LDS dest offset within the 4 KiB quarter

  int32x4 acc[4][4] = {};

  for (int k0 = 0; k0 < K; k0 += BK) {
#pragma unroll
    for (int p = 0; p < 4; ++p) {
      const int rr = p * 32 + row_s;
      async_copy16(A8 + (size_t)(row0 + rr) * sK + k0 + cg * 16,
                   &As[p * 4096 + ldst]);
      async_copy16(B8 + (size_t)(col0 + rr) * sK + k0 + cg * 16,
                   &Bs[p * 4096 + ldst]);
    }
    __syncthreads();  // drains vmcnt(0)

#pragma unroll
    for (int s = 0; s < 2; ++s) {
      int32x4 afrag[4], bfrag[4];
      const int swzr = (r >> 1) & 7;
      const int cslot = ((s * 4 + quad) ^ swzr) * 16;
#pragma unroll
      for (int i = 0; i < 4; ++i)
        afrag[i] = *(const int32x4*)&As[(wm + i * 16 + r) * BK + cslot];
#pragma unroll
      for (int j = 0; j < 4; ++j)
        bfrag[j] = *(const int32x4*)&Bs[(wn + j * 16 + r) * BK + cslot];
#pragma unroll
      for (int i = 0; i < 4; ++i)
#pragma unroll
        for (int j = 0; j < 4; ++j)
          acc[i][j] = __builtin_amdgcn_mfma_i32_16x16x64_i8(
              afrag[i], bfrag[j], acc[i][j], 0, 0, 0);
    }
    __syncthreads();
  }

  // Epilogue: C/D layout col=lane&15, row=quad*4+reg.
  float swj[4], zpj[4], bj[4];
#pragma unroll
  for (int j = 0; j < 4; ++j) {
    int gc = col0 + wn + j * 16 + r;
    swj[j] = s_w[gc];
    zpj[j] = (float)zp_w[gc];
    bj[j] = bias[gc];
  }
#pragma unroll
  for (int i = 0; i < 4; ++i) {
#pragma unroll
    for (int t = 0; t < 4; ++t) {
      int gr = row0 + wm + i * 16 + quad * 4 + t;
      float siv = s_in[gr];
      float suv = sum_in[gr];
      float* orow = out + (size_t)gr * N + col0 + wn + r;
#pragma unroll
      for (int j = 0; j < 4; ++j) {
        float v = ((float)acc[i][j][t] + suv * zpj[j]) * (siv * swj[j]) + bj[j];
        orow[j * 16] = v;
      }
    }
  }
}

// Fallback (ws too small): unpacked int32 inputs, BK=64, VALU pack + ds_write.
__global__ __launch_bounds__(256) void w8a8_gemm_fallback(
    const int* __restrict__ A32, const int* __restrict__ B32,
    const float* __restrict__ bias,
    const float* __restrict__ s_in,
    const float* __restrict__ s_w,
    const float* __restrict__ sum_in,
    const int* __restrict__ zp_w,
    float* __restrict__ out,
    int M, int N, int K) {
  __shared__ uint8_t As[128 * 64];
  __shared__ uint8_t Bs[128 * 64];
  const int tid = threadIdx.x;
  const int bm = blockIdx.y, bn = blockIdx.x;
  const int row0 = bm * 128, col0 = bn * 128;
  const int wave = tid >> 6, lane = tid & 63;
  const int quad = lane >> 4, r = lane & 15;
  const int wm = (wave >> 1) * 64, wn = (wave & 1) * 64;
  const int lin = tid * 16;
  const int srow = lin >> 6;
  const int scol = lin & 63;
  const size_t sK = (size_t)K;
  int32x4 acc[4][4] = {};
  for (int k0 = 0; k0 < K; k0 += 64) {
#pragma unroll
    for (int c = 0; c < 2; ++c) {
      const int* ag = A32 + (size_t)(row0 + srow + c * 64) * sK + k0 + scol;
      const int* bg = B32 + (size_t)(col0 + srow + c * 64) * sK + k0 + scol;
      int32x4 pa, pb;
#pragma unroll
      for (int q = 0; q < 4; ++q) {
        int4 va = ((const int4*)ag)[q];
        int4 vb = ((const int4*)bg)[q];
        pa[q] = (int)((uint32_t)(va.x & 255) | ((uint32_t)(va.y & 255) << 8) |
                      ((uint32_t)(va.z & 255) << 16) | ((uint32_t)(va.w & 255) << 24));
        pb[q] = (int)((uint32_t)(vb.x & 255) | ((uint32_t)(vb.y & 255) << 8) |
                      ((uint32_t)(vb.z & 255) << 16) | ((uint32_t)(vb.w & 255) << 24));
      }
      *(int32x4*)&As[lin + c * 4096] = pa;
      *(int32x4*)&Bs[lin + c * 4096] = pb;
    }
    __syncthreads();
    int32x4 afrag[4], bfrag[4];
#pragma unroll
    for (int i = 0; i < 4; ++i)
      afrag[i] = *(const int32x4*)&As[(wm + i * 16 + r) * 64 + quad * 16];
#pragma unroll
    for (int j = 0; j < 4; ++j)
      bfrag[j] = *(const int32x4*)&Bs[(wn + j * 16 + r) * 64 + quad * 16];
#pragma unroll
    for (int i = 0; i < 4; ++i)
#pragma unroll
      for (int j = 0; j < 4; ++j)
        acc[i][j] = __builtin_amdgcn_mfma_i32_16x16x64_i8(afrag[i], bfrag[j],
                                                          acc[i][j], 0, 0, 0);
    __syncthreads();
  }
  float swj[4], zpj[4], bj[4];
#pragma unroll
  for (int j = 0; j < 4; ++j) {
    int gc = col0 + wn + j * 16 + r;
    swj[j] = s_w[gc];
    zpj[j] = (float)zp_w[gc];
    bj[j] = bias[gc];
  }
#pragma unroll
  for (int i = 0; i < 4; ++i) {
#pragma unroll
    for (int t = 0; t < 4; ++t) {
      int gr = row0 + wm + i * 16 + quad * 4 + t;
      float siv = s_in[gr];
      float suv = sum_in[gr];
      float* orow = out + (size_t)gr * N + col0 + wn + r;
#pragma unroll
      for (int j = 0; j < 4; ++j) {
        float v = ((float)acc[i][j][t] + suv * zpj[j]) * (siv * swj[j]) + bj[j];
        orow[j * 16] = v;
      }
    }
  }
}

extern "C" void kernel_launch(void* const* d_in, const int* in_sizes, int n_in,
                              void* d_out, int out_size, void* d_ws, size_t ws_size,
                              hipStream_t stream) {
  const int* x_q = (const int*)d_in[0];
  const int* w_q = (const int*)d_in[1];
  const float* bias = (const float*)d_in[2];
  const float* s_in = (const float*)d_in[3];
  const float* s_w = (const float*)d_in[4];
  const float* sum_in = (const float*)d_in[5];
  const int* zp_w = (const int*)d_in[6];
  float* out = (float*)d_out;

  const int M = in_sizes[3];
  const int N = in_sizes[2];
  const int K = in_sizes[0] / M;

  const size_t needA = (size_t)M * K;
  const size_t needB = (size_t)N * K;
  dim3 grid(N / BN, M / BM), block(256);

  if (ws_size >= needA + needB) {
    uint8_t* A8 = (uint8_t*)d_ws;
    uint8_t* B8 = A8 + needA;
    const int nA4 = (int)(needA / 4);
    const int nTot4 = (int)((needA + needB) / 4);
    pack_kernel<<<(nTot4 + 255) / 256, 256, 0, stream>>>(x_q, w_q, A8, B8,
                                                         nA4, nTot4);
    w8a8_gemm<<<grid, block, 0, stream>>>(A8, B8, bias, s_in, s_w, sum_in,
                                          zp_w, out, M, N, K);
  } else {
    w8a8_gemm_fallback<<<grid, block, 0, stream>>>(x_q, w_q, bias, s_in, s_w,
                                                   sum_in, zp_w, out, M, N, K);
  }
}

// Round 5
// 406.274 us; speedup vs baseline: 1.1522x; 1.0388x over previous
//
#include <hip/hip_runtime.h>
#include <hip/hip_bf16.h>
#include <stdint.h>

// W8A8 int8 GEMM + dequant epilogue, MI355X gfx950.
// R5: fix R4 compile error — __builtin_nontemporal_load needs ext_vector_type,
// not HIP_vector_type. Otherwise identical to R4:
// mfma_i32_32x32x32_i8 (4404 TOPS ceiling vs 3944), nontemporal output
// stores (keep A8/B8 L3-resident), nontemporal pack loads.
// out[m,n] = (sum_k A*W + sum_input[m]*zp_w[n]) * si[m]*sw[n] + bias[n]

#define BM 128
#define BN 128
#define BK 128

typedef __attribute__((ext_vector_type(4))) int int32x4;
typedef __attribute__((ext_vector_type(16))) int int32x16;

__device__ __forceinline__ void async_copy16(const uint8_t* g, uint8_t* l) {
  __builtin_amdgcn_global_load_lds(
      (const __attribute__((address_space(1))) uint32_t*)(const void*)g,
      (__attribute__((address_space(3))) uint32_t*)l,
      16, 0, 0);
}

// Coalesced pack — one int32x4 (4 int8-as-int32) per thread -> one uint32.
__global__ __launch_bounds__(256) void pack_kernel(
    const int* __restrict__ A, const int* __restrict__ B,
    uint8_t* __restrict__ A8, uint8_t* __restrict__ B8,
    int nA4, int nTot4) {
  int t = blockIdx.x * blockDim.x + threadIdx.x;
  if (t >= nTot4) return;
  const int32x4* src;
  uint32_t* dst;
  if (t < nA4) {
    src = (const int32x4*)A + t;
    dst = (uint32_t*)A8 + t;
  } else {
    int u = t - nA4;
    src = (const int32x4*)B + u;
    dst = (uint32_t*)B8 + u;
  }
  int32x4 v = __builtin_nontemporal_load(src);  // read-once stream
  // packed store stays cacheable: GEMM re-reads it
  *dst = (uint32_t)(v.x & 255) | ((uint32_t)(v.y & 255) << 8) |
         ((uint32_t)(v.z & 255) << 16) | ((uint32_t)(v.w & 255) << 24);
}

// Packed-path GEMM: BK=128, XOR-swizzled LDS chunks, 32x32x32 i8 MFMA.
// LDS layout: row r (128 B) stores global chunk cg at slot cs = cg ^ ((r>>1)&7).
__global__ __launch_bounds__(256) void w8a8_gemm(
    const uint8_t* __restrict__ A8, const uint8_t* __restrict__ B8,
    const float* __restrict__ bias,
    const float* __restrict__ s_in,
    const float* __restrict__ s_w,
    const float* __restrict__ sum_in,
    const int* __restrict__ zp_w,
    float* __restrict__ out,
    int M, int N, int K) {
  __shared__ uint8_t As[BM * BK];  // 16 KiB
  __shared__ uint8_t Bs[BN * BK];  // 16 KiB

  const int tid = threadIdx.x;
  const int bm = blockIdx.y, bn = blockIdx.x;
  const int row0 = bm * BM, col0 = bn * BN;
  const int wave = tid >> 6, lane = tid & 63;
  const int m32 = lane & 31, half = lane >> 5;
  const int wm = (wave >> 1) * 64, wn = (wave & 1) * 64;
  const size_t sK = (size_t)K;

  // staging: issue p (0..3) covers rows [p*32, p*32+32); thread owns
  // row_s = tid>>3, stored chunk cs = tid&7, global chunk cg = cs ^ ((row>>1)&7).
  const int row_s = tid >> 3;
  const int cg = (tid & 7) ^ ((tid >> 4) & 7);
  const int ldst = tid * 16;

  int32x16 acc[2][2] = {};

  for (int k0 = 0; k0 < K; k0 += BK) {
#pragma unroll
    for (int p = 0; p < 4; ++p) {
      const int rr = p * 32 + row_s;
      async_copy16(A8 + (size_t)(row0 + rr) * sK + k0 + cg * 16,
                   &As[p * 4096 + ldst]);
      async_copy16(B8 + (size_t)(col0 + rr) * sK + k0 + cg * 16,
                   &Bs[p * 4096 + ldst]);
    }
    __syncthreads();  // drains vmcnt(0)

    const int swzr = (m32 >> 1) & 7;
#pragma unroll
    for (int ks = 0; ks < 4; ++ks) {
      // A/B fragment: elem k = ks*32 + half*16 + j (j=0..15), row = m/n index.
      const int gran = ((ks * 2 + half) ^ swzr) * 16;
      int32x4 afrag[2], bfrag[2];
#pragma unroll
      for (int i = 0; i < 2; ++i)
        afrag[i] = *(const int32x4*)&As[(wm + i * 32 + m32) * BK + gran];
#pragma unroll
      for (int j = 0; j < 2; ++j)
        bfrag[j] = *(const int32x4*)&Bs[(wn + j * 32 + m32) * BK + gran];
#pragma unroll
      for (int i = 0; i < 2; ++i)
#pragma unroll
        for (int j = 0; j < 2; ++j)
          acc[i][j] = __builtin_amdgcn_mfma_i32_32x32x32_i8(
              afrag[i], bfrag[j], acc[i][j], 0, 0, 0);
    }
    __syncthreads();
  }

  // Epilogue: 32x32 C/D layout col=lane&31, row=(reg&3)+8*(reg>>2)+4*(lane>>5).
  float swj[2], zpj[2], bj[2];
#pragma unroll
  for (int j = 0; j < 2; ++j) {
    int gc = col0 + wn + j * 32 + m32;
    swj[j] = s_w[gc];
    zpj[j] = (float)zp_w[gc];
    bj[j] = bias[gc];
  }
#pragma unroll
  for (int i = 0; i < 2; ++i) {
#pragma unroll
    for (int reg = 0; reg < 16; ++reg) {
      int gr = row0 + wm + i * 32 + (reg & 3) + 8 * (reg >> 2) + 4 * half;
      float siv = s_in[gr];
      float suv = sum_in[gr];
      float* orow = out + (size_t)gr * N + col0 + wn + m32;
#pragma unroll
      for (int j = 0; j < 2; ++j) {
        float v = ((float)acc[i][j][reg] + suv * zpj[j]) * (siv * swj[j]) + bj[j];
        __builtin_nontemporal_store(v, &orow[j * 32]);  // don't evict A8/B8
      }
    }
  }
}

// Fallback (ws too small): unpacked int32 inputs, BK=64, VALU pack + ds_write.
__global__ __launch_bounds__(256) void w8a8_gemm_fallback(
    const int* __restrict__ A32, const int* __restrict__ B32,
    const float* __restrict__ bias,
    const float* __restrict__ s_in,
    const float* __restrict__ s_w,
    const float* __restrict__ sum_in,
    const int* __restrict__ zp_w,
    float* __restrict__ out,
    int M, int N, int K) {
  __shared__ uint8_t As[128 * 64];
  __shared__ uint8_t Bs[128 * 64];
  const int tid = threadIdx.x;
  const int bm = blockIdx.y, bn = blockIdx.x;
  const int row0 = bm * 128, col0 = bn * 128;
  const int wave = tid >> 6, lane = tid & 63;
  const int quad = lane >> 4, r = lane & 15;
  const int wm = (wave >> 1) * 64, wn = (wave & 1) * 64;
  const int lin = tid * 16;
  const int srow = lin >> 6;
  const int scol = lin & 63;
  const size_t sK = (size_t)K;
  int32x4 acc[4][4] = {};
  for (int k0 = 0; k0 < K; k0 += 64) {
#pragma unroll
    for (int c = 0; c < 2; ++c) {
      const int* ag = A32 + (size_t)(row0 + srow + c * 64) * sK + k0 + scol;
      const int* bg = B32 + (size_t)(col0 + srow + c * 64) * sK + k0 + scol;
      int32x4 pa, pb;
#pragma unroll
      for (int q = 0; q < 4; ++q) {
        int4 va = ((const int4*)ag)[q];
        int4 vb = ((const int4*)bg)[q];
        pa[q] = (int)((uint32_t)(va.x & 255) | ((uint32_t)(va.y & 255) << 8) |
                      ((uint32_t)(va.z & 255) << 16) | ((uint32_t)(va.w & 255) << 24));
        pb[q] = (int)((uint32_t)(vb.x & 255) | ((uint32_t)(vb.y & 255) << 8) |
                      ((uint32_t)(vb.z & 255) << 16) | ((uint32_t)(vb.w & 255) << 24));
      }
      *(int32x4*)&As[lin + c * 4096] = pa;
      *(int32x4*)&Bs[lin + c * 4096] = pb;
    }
    __syncthreads();
    int32x4 afrag[4], bfrag[4];
#pragma unroll
    for (int i = 0; i < 4; ++i)
      afrag[i] = *(const int32x4*)&As[(wm + i * 16 + r) * 64 + quad * 16];
#pragma unroll
    for (int j = 0; j < 4; ++j)
      bfrag[j] = *(const int32x4*)&Bs[(wn + j * 16 + r) * 64 + quad * 16];
#pragma unroll
    for (int i = 0; i < 4; ++i)
#pragma unroll
      for (int j = 0; j < 4; ++j)
        acc[i][j] = __builtin_amdgcn_mfma_i32_16x16x64_i8(afrag[i], bfrag[j],
                                                          acc[i][j], 0, 0, 0);
    __syncthreads();
  }
  float swj[4], zpj[4], bj[4];
#pragma unroll
  for (int j = 0; j < 4; ++j) {
    int gc = col0 + wn + j * 16 + r;
    swj[j] = s_w[gc];
    zpj[j] = (float)zp_w[gc];
    bj[j] = bias[gc];
  }
#pragma unroll
  for (int i = 0; i < 4; ++i) {
#pragma unroll
    for (int t = 0; t < 4; ++t) {
      int gr = row0 + wm + i * 16 + quad * 4 + t;
      float siv = s_in[gr];
      float suv = sum_in[gr];
      float* orow = out + (size_t)gr * N + col0 + wn + r;
#pragma unroll
      for (int j = 0; j < 4; ++j) {
        float v = ((float)acc[i][j][t] + suv * zpj[j]) * (siv * swj[j]) + bj[j];
        orow[j * 16] = v;
      }
    }
  }
}

extern "C" void kernel_launch(void* const* d_in, const int* in_sizes, int n_in,
                              void* d_out, int out_size, void* d_ws, size_t ws_size,
                              hipStream_t stream) {
  const int* x_q = (const int*)d_in[0];
  const int* w_q = (const int*)d_in[1];
  const float* bias = (const float*)d_in[2];
  const float* s_in = (const float*)d_in[3];
  const float* s_w = (const float*)d_in[4];
  const float* sum_in = (const float*)d_in[5];
  const int* zp_w = (const int*)d_in[6];
  float* out = (float*)d_out;

  const int M = in_sizes[3];
  const int N = in_sizes[2];
  const int K = in_sizes[0] / M;

  const size_t needA = (size_t)M * K;
  const size_t needB = (size_t)N * K;
  dim3 grid(N / BN, M / BM), block(256);

  if (ws_size >= needA + needB) {
    uint8_t* A8 = (uint8_t*)d_ws;
    uint8_t* B8 = A8 + needA;
    const int nA4 = (int)(needA / 4);
    const int nTot4 = (int)((needA + needB) / 4);
    pack_kernel<<<(nTot4 + 255) / 256, 256, 0, stream>>>(x_q, w_q, A8, B8,
                                                         nA4, nTot4);
    w8a8_gemm<<<grid, block, 0, stream>>>(A8, B8, bias, s_in, s_w, sum_in,
                                          zp_w, out, M, N, K);
  } else {
    w8a8_gemm_fallback<<<grid, block, 0, stream>>>(x_q, w_q, bias, s_in, s_w,
                                                   sum_in, zp_w, out, M, N, K);
  }
}

// Round 6
// 394.957 us; speedup vs baseline: 1.1852x; 1.0287x over previous
//
#include <hip/hip_runtime.h>
#include <hip/hip_bf16.h>
#include <stdint.h>

// W8A8 int8 GEMM + dequant epilogue, MI355X gfx950.
// R6: wave tile 64x128 (block 256x128) — raises MACs per LDS-byte from 32
// to 42.7; i8 MFMA is LDS-read-bound at 64x64 wave tiles (MfmaUtil capped
// ~50%, measured 37%). acc 2x4 of 32x32, afrag[2]/bfrag[4].
// out[m,n] = (sum_k A*W + sum_input[m]*zp_w[n]) * si[m]*sw[n] + bias[n]

#define BM 256
#define BN 128
#define BK 128

typedef __attribute__((ext_vector_type(4))) int int32x4;
typedef __attribute__((ext_vector_type(16))) int int32x16;

__device__ __forceinline__ void async_copy16(const uint8_t* g, uint8_t* l) {
  __builtin_amdgcn_global_load_lds(
      (const __attribute__((address_space(1))) uint32_t*)(const void*)g,
      (__attribute__((address_space(3))) uint32_t*)l,
      16, 0, 0);
}

// Coalesced pack — one int32x4 (4 int8-as-int32) per thread -> one uint32.
__global__ __launch_bounds__(256) void pack_kernel(
    const int* __restrict__ A, const int* __restrict__ B,
    uint8_t* __restrict__ A8, uint8_t* __restrict__ B8,
    int nA4, int nTot4) {
  int t = blockIdx.x * blockDim.x + threadIdx.x;
  if (t >= nTot4) return;
  const int32x4* src;
  uint32_t* dst;
  if (t < nA4) {
    src = (const int32x4*)A + t;
    dst = (uint32_t*)A8 + t;
  } else {
    int u = t - nA4;
    src = (const int32x4*)B + u;
    dst = (uint32_t*)B8 + u;
  }
  int32x4 v = __builtin_nontemporal_load(src);  // read-once stream
  *dst = (uint32_t)(v.x & 255) | ((uint32_t)(v.y & 255) << 8) |
         ((uint32_t)(v.z & 255) << 16) | ((uint32_t)(v.w & 255) << 24);
}

// Packed-path GEMM: BM=256/BN=128/BK=128, XOR-swizzled LDS, 32x32x32 i8 MFMA.
// LDS row r (128 B) stores global chunk cg at slot cs = cg ^ ((r>>1)&7).
// Verified conflict-free (R3/R5: SQ_LDS_BANK_CONFLICT == 0).
__global__ __launch_bounds__(256, 2) void w8a8_gemm(
    const uint8_t* __restrict__ A8, const uint8_t* __restrict__ B8,
    const float* __restrict__ bias,
    const float* __restrict__ s_in,
    const float* __restrict__ s_w,
    const float* __restrict__ sum_in,
    const int* __restrict__ zp_w,
    float* __restrict__ out,
    int M, int N, int K) {
  __shared__ uint8_t As[BM * BK];  // 32 KiB
  __shared__ uint8_t Bs[BN * BK];  // 16 KiB

  const int tid = threadIdx.x;
  const int bm = blockIdx.y, bn = blockIdx.x;
  const int row0 = bm * BM, col0 = bn * BN;
  const int wave = tid >> 6, lane = tid & 63;
  const int m32 = lane & 31, half = lane >> 5;
  const int wm = wave * 64;  // 4 waves stacked along m; each wave spans all BN
  const size_t sK = (size_t)K;

  // staging: issue p covers rows [p*32, p*32+32); thread owns
  // row_s = tid>>3, stored chunk cs = tid&7, global chunk cg = cs ^ ((row>>1)&7).
  const int row_s = tid >> 3;
  const int cg = (tid & 7) ^ ((tid >> 4) & 7);
  const int ldst = tid * 16;

  int32x16 acc[2][4] = {};

  for (int k0 = 0; k0 < K; k0 += BK) {
#pragma unroll
    for (int p = 0; p < 8; ++p)
      async_copy16(A8 + (size_t)(row0 + p * 32 + row_s) * sK + k0 + cg * 16,
                   &As[p * 4096 + ldst]);
#pragma unroll
    for (int p = 0; p < 4; ++p)
      async_copy16(B8 + (size_t)(col0 + p * 32 + row_s) * sK + k0 + cg * 16,
                   &Bs[p * 4096 + ldst]);
    __syncthreads();  // drains vmcnt(0)

    const int swzr = (m32 >> 1) & 7;
#pragma unroll
    for (int ks = 0; ks < 4; ++ks) {
      const int gran = ((ks * 2 + half) ^ swzr) * 16;
      int32x4 afrag[2], bfrag[4];
#pragma unroll
      for (int i = 0; i < 2; ++i)
        afrag[i] = *(const int32x4*)&As[(wm + i * 32 + m32) * BK + gran];
#pragma unroll
      for (int j = 0; j < 4; ++j)
        bfrag[j] = *(const int32x4*)&Bs[(j * 32 + m32) * BK + gran];
#pragma unroll
      for (int i = 0; i < 2; ++i)
#pragma unroll
        for (int j = 0; j < 4; ++j)
          acc[i][j] = __builtin_amdgcn_mfma_i32_32x32x32_i8(
              afrag[i], bfrag[j], acc[i][j], 0, 0, 0);
    }
    __syncthreads();
  }

  // Epilogue: 32x32 C/D layout col=lane&31, row=(reg&3)+8*(reg>>2)+4*(lane>>5).
  float swj[4], zpj[4], bj[4];
#pragma unroll
  for (int j = 0; j < 4; ++j) {
    int gc = col0 + j * 32 + m32;
    swj[j] = s_w[gc];
    zpj[j] = (float)zp_w[gc];
    bj[j] = bias[gc];
  }
#pragma unroll
  for (int i = 0; i < 2; ++i) {
#pragma unroll
    for (int reg = 0; reg < 16; ++reg) {
      int gr = row0 + wm + i * 32 + (reg & 3) + 8 * (reg >> 2) + 4 * half;
      float siv = s_in[gr];
      float suv = sum_in[gr];
      float* orow = out + (size_t)gr * N + col0 + m32;
#pragma unroll
      for (int j = 0; j < 4; ++j) {
        float v = ((float)acc[i][j][reg] + suv * zpj[j]) * (siv * swj[j]) + bj[j];
        __builtin_nontemporal_store(v, &orow[j * 32]);
      }
    }
  }
}

// Fallback (ws too small): unpacked int32 inputs, BK=64, VALU pack + ds_write.
__global__ __launch_bounds__(256) void w8a8_gemm_fallback(
    const int* __restrict__ A32, const int* __restrict__ B32,
    const float* __restrict__ bias,
    const float* __restrict__ s_in,
    const float* __restrict__ s_w,
    const float* __restrict__ sum_in,
    const int* __restrict__ zp_w,
    float* __restrict__ out,
    int M, int N, int K) {
  __shared__ uint8_t As[128 * 64];
  __shared__ uint8_t Bs[128 * 64];
  const int tid = threadIdx.x;
  const int bm = blockIdx.y, bn = blockIdx.x;
  const int row0 = bm * 128, col0 = bn * 128;
  const int wave = tid >> 6, lane = tid & 63;
  const int quad = lane >> 4, r = lane & 15;
  const int wm = (wave >> 1) * 64, wn = (wave & 1) * 64;
  const int lin = tid * 16;
  const int srow = lin >> 6;
  const int scol = lin & 63;
  const size_t sK = (size_t)K;
  int32x4 acc[4][4] = {};
  for (int k0 = 0; k0 < K; k0 += 64) {
#pragma unroll
    for (int c = 0; c < 2; ++c) {
      const int* ag = A32 + (size_t)(row0 + srow + c * 64) * sK + k0 + scol;
      const int* bg = B32 + (size_t)(col0 + srow + c * 64) * sK + k0 + scol;
      int32x4 pa, pb;
#pragma unroll
      for (int q = 0; q < 4; ++q) {
        int4 va = ((const int4*)ag)[q];
        int4 vb = ((const int4*)bg)[q];
        pa[q] = (int)((uint32_t)(va.x & 255) | ((uint32_t)(va.y & 255) << 8) |
                      ((uint32_t)(va.z & 255) << 16) | ((uint32_t)(va.w & 255) << 24));
        pb[q] = (int)((uint32_t)(vb.x & 255) | ((uint32_t)(vb.y & 255) << 8) |
                      ((uint32_t)(vb.z & 255) << 16) | ((uint32_t)(vb.w & 255) << 24));
      }
      *(int32x4*)&As[lin + c * 4096] = pa;
      *(int32x4*)&Bs[lin + c * 4096] = pb;
    }
    __syncthreads();
    int32x4 afrag[4], bfrag[4];
#pragma unroll
    for (int i = 0; i < 4; ++i)
      afrag[i] = *(const int32x4*)&As[(wm + i * 16 + r) * 64 + quad * 16];
#pragma unroll
    for (int j = 0; j < 4; ++j)
      bfrag[j] = *(const int32x4*)&Bs[(wn + j * 16 + r) * 64 + quad * 16];
#pragma unroll
    for (int i = 0; i < 4; ++i)
#pragma unroll
      for (int j = 0; j < 4; ++j)
        acc[i][j] = __builtin_amdgcn_mfma_i32_16x16x64_i8(afrag[i], bfrag[j],
                                                          acc[i][j], 0, 0, 0);
    __syncthreads();
  }
  float swj[4], zpj[4], bj[4];
#pragma unroll
  for (int j = 0; j < 4; ++j) {
    int gc = col0 + wn + j * 16 + r;
    swj[j] = s_w[gc];
    zpj[j] = (float)zp_w[gc];
    bj[j] = bias[gc];
  }
#pragma unroll
  for (int i = 0; i < 4; ++i) {
#pragma unroll
    for (int t = 0; t < 4; ++t) {
      int gr = row0 + wm + i * 16 + quad * 4 + t;
      float siv = s_in[gr];
      float suv = sum_in[gr];
      float* orow = out + (size_t)gr * N + col0 + wn + r;
#pragma unroll
      for (int j = 0; j < 4; ++j) {
        float v = ((float)acc[i][j][t] + suv * zpj[j]) * (siv * swj[j]) + bj[j];
        orow[j * 16] = v;
      }
    }
  }
}

extern "C" void kernel_launch(void* const* d_in, const int* in_sizes, int n_in,
                              void* d_out, int out_size, void* d_ws, size_t ws_size,
                              hipStream_t stream) {
  const int* x_q = (const int*)d_in[0];
  const int* w_q = (const int*)d_in[1];
  const float* bias = (const float*)d_in[2];
  const float* s_in = (const float*)d_in[3];
  const float* s_w = (const float*)d_in[4];
  const float* sum_in = (const float*)d_in[5];
  const int* zp_w = (const int*)d_in[6];
  float* out = (float*)d_out;

  const int M = in_sizes[3];
  const int N = in_sizes[2];
  const int K = in_sizes[0] / M;

  const size_t needA = (size_t)M * K;
  const size_t needB = (size_t)N * K;

  if (ws_size >= needA + needB) {
    uint8_t* A8 = (uint8_t*)d_ws;
    uint8_t* B8 = A8 + needA;
    const int nA4 = (int)(needA / 4);
    const int nTot4 = (int)((needA + needB) / 4);
    pack_kernel<<<(nTot4 + 255) / 256, 256, 0, stream>>>(x_q, w_q, A8, B8,
                                                         nA4, nTot4);
    dim3 grid(N / BN, M / BM), block(256);
    w8a8_gemm<<<grid, block, 0, stream>>>(A8, B8, bias, s_in, s_w, sum_in,
                                          zp_w, out, M, N, K);
  } else {
    dim3 grid(N / 128, M / 128), block(256);
    w8a8_gemm_fallback<<<grid, block, 0, stream>>>(x_q, w_q, bias, s_in, s_w,
                                                   sum_in, zp_w, out, M, N, K);
  }
}